// Round 1
// baseline (212.733 us; speedup 1.0000x reference)
//
#include <hip/hip_runtime.h>

// Trilinear 3D-LUT apply: lut [1,3,33,33,33] f32, x [8,3,1024,1024] f32 in [0,1]
// out [8,3,1024,1024] f32.
//
// Strategy: indices are uniform-random over a 431 KB LUT -> global-memory
// gathers would be L2-bound (~12 GB of 64B-line traffic). Instead, split by
// output channel: one 33^3 cube = 143.7 KB fits in the 160 KB LDS. Each block
// stages one channel cube into LDS and computes that channel for a chunk of
// pixels. grid=(3, CHUNKS): channel is the fastest dispatch dim so the three
// blocks sharing an x-chunk co-schedule -> x re-reads hit L2/L3.

#define D   33
#define D2  (33 * 33)
#define D3  (33 * 33 * 33)      // 35937 floats = 143,748 B LDS
#define HW  (1024 * 1024)
#define BATCH 8
#define QHW (HW / 4)            // float4 groups per plane
#define NG  (BATCH * QHW)       // float4 groups per channel total = 2,097,152
#define CHUNKS 256
#define GPC (NG / CHUNKS)       // groups per chunk = 8192
#define THREADS 1024

__global__ __launch_bounds__(THREADS) void lut3d_kernel(
    const float* __restrict__ lut, const float* __restrict__ x,
    float* __restrict__ out)
{
    const int c     = blockIdx.x;   // output channel 0..2
    const int chunk = blockIdx.y;   // pixel chunk

    __shared__ float ls[D3];
    {
        const float* lc = lut + c * D3;
        for (int i = threadIdx.x; i < D3; i += THREADS) ls[i] = lc[i];
    }
    __syncthreads();

    const int tid  = threadIdx.x;
    const int base = chunk * GPC;

    #pragma unroll 1
    for (int it = 0; it < GPC / THREADS; ++it) {
        const int g = base + it * THREADS + tid;       // float4-group id
        const int b = g >> 18;                         // g / QHW (QHW = 2^18)
        const int p = (g & (QHW - 1)) * 4;             // pixel offset in plane

        const float* xb = x + (size_t)b * 3 * HW + p;
        const float4 xr = *(const float4*)(xb);
        const float4 xg = *(const float4*)(xb + HW);
        const float4 xB = *(const float4*)(xb + 2 * HW);

        const float rr[4] = {xr.x, xr.y, xr.z, xr.w};
        const float gg[4] = {xg.x, xg.y, xg.z, xg.w};
        const float bb[4] = {xB.x, xB.y, xB.z, xB.w};
        float oo[4];

        #pragma unroll
        for (int j = 0; j < 4; ++j) {
            const float vr = fminf(fmaxf(rr[j], 0.f), 1.f) * 32.f;
            const float vg = fminf(fmaxf(gg[j], 0.f), 1.f) * 32.f;
            const float vb = fminf(fmaxf(bb[j], 0.f), 1.f) * 32.f;

            const float r0f = floorf(vr);
            const float g0f = floorf(vg);
            const float b0f = floorf(vb);
            const int r0 = (int)r0f, g0 = (int)g0f, b0 = (int)b0f;
            const float fr = vr - r0f, fg = vg - g0f, fb = vb - b0f;

            const int dr = (r0 < D - 1) ? D2 : 0;
            const int dg = (g0 < D - 1) ? D  : 0;
            const int db = (b0 < D - 1) ? 1  : 0;
            const int idx = r0 * D2 + g0 * D + b0;

            const float c000 = ls[idx];
            const float c001 = ls[idx + db];
            const float c010 = ls[idx + dg];
            const float c011 = ls[idx + dg + db];
            const float c100 = ls[idx + dr];
            const float c101 = ls[idx + dr + db];
            const float c110 = ls[idx + dr + dg];
            const float c111 = ls[idx + dr + dg + db];

            // lerp b, then g, then r — identical to the 8-weight sum
            const float c00 = c000 + fb * (c001 - c000);
            const float c01 = c010 + fb * (c011 - c010);
            const float c10 = c100 + fb * (c101 - c100);
            const float c11 = c110 + fb * (c111 - c110);
            const float c0  = c00 + fg * (c01 - c00);
            const float c1  = c10 + fg * (c11 - c10);
            oo[j] = c0 + fr * (c1 - c0);
        }

        float* ob = out + (size_t)b * 3 * HW + (size_t)c * HW + p;
        *(float4*)ob = make_float4(oo[0], oo[1], oo[2], oo[3]);
    }
}

extern "C" void kernel_launch(void* const* d_in, const int* in_sizes, int n_in,
                              void* d_out, int out_size, void* d_ws, size_t ws_size,
                              hipStream_t stream) {
    const float* lut = (const float*)d_in[0];   // [1,3,33,33,33]
    const float* x   = (const float*)d_in[1];   // [8,3,1024,1024]
    float* out = (float*)d_out;                 // [8,3,1024,1024]

    dim3 grid(3, CHUNKS);
    lut3d_kernel<<<grid, THREADS, 0, stream>>>(lut, x, out);
}